// Round 3
// baseline (891.034 us; speedup 1.0000x reference)
//
#include <hip/hip_runtime.h>

#define BB 64
#define NN 1024
#define CC 512
#define MM 16
#define SCALE 0.04419417382415922f  // 1/sqrt(512)

__device__ __forceinline__ float dot4(float4 a, float4 b) {
  return a.x*b.x + a.y*b.y + a.z*b.z + a.w*b.w;
}

// ---------------------------------------------------------------------------
// P[b,m,c] = mean over 64 tokens. grid 1024 (b*16+m), block 256 (2-way split).
__global__ void k_pool2(const float* __restrict__ x, float* __restrict__ P) {
  __shared__ float4 tmp[128];
  int blk = blockIdx.x;        // b*16+m
  int t = threadIdx.x;
  int c4 = t & 127, h = t >> 7;
  const float4* base = (const float4*)(x + (size_t)blk * 64 * CC);
  float4 a = {0.f,0.f,0.f,0.f};
  #pragma unroll 8
  for (int i = 0; i < 32; ++i) {
    float4 v = base[(size_t)(h*32 + i)*128 + c4];
    a.x += v.x; a.y += v.y; a.z += v.z; a.w += v.w;
  }
  if (h == 1) tmp[c4] = a;
  __syncthreads();
  if (h == 0) {
    float4 o = tmp[c4];
    const float inv = 1.0f/64.0f;
    float4 r = {(a.x+o.x)*inv, (a.y+o.y)*inv, (a.z+o.z)*inv, (a.w+o.w)*inv};
    ((float4*)P)[(size_t)blk*128 + c4] = r;
  }
}

// ---------------------------------------------------------------------------
// Out[r,d] = sum_c In[r,c]*W[d,c] + bias[d]. grid (16,32), block 256.
__global__ void k_gemm_nt(const float* __restrict__ In, const float* __restrict__ W,
                          const float* __restrict__ bias, float* __restrict__ Out) {
  int t = threadIdx.x;
  int tx = t & 15, ty = t >> 4;
  int r0 = blockIdx.y*32 + ty*2;
  int d0 = blockIdx.x*32 + tx*2;
  const float4* In4 = (const float4*)In;
  const float4* W4  = (const float4*)W;
  float acc00=0.f, acc01=0.f, acc10=0.f, acc11=0.f;
  for (int c4 = 0; c4 < 128; ++c4) {
    float4 a0 = In4[(size_t)r0*128 + c4];
    float4 a1 = In4[(size_t)(r0+1)*128 + c4];
    float4 w0 = W4[(size_t)d0*128 + c4];
    float4 w1 = W4[(size_t)(d0+1)*128 + c4];
    acc00 += dot4(a0,w0); acc01 += dot4(a0,w1);
    acc10 += dot4(a1,w0); acc11 += dot4(a1,w1);
  }
  float b0 = bias[d0], b1 = bias[d0+1];
  float2 o0 = {acc00+b0, acc01+b1};
  float2 o1 = {acc10+b0, acc11+b1};
  *(float2*)(Out + (size_t)r0*CC + d0) = o0;
  *(float2*)(Out + (size_t)(r0+1)*CC + d0) = o1;
}

// ---------------------------------------------------------------------------
// abq[bm] = A[bm,:].bq ; abk[bm] = A[bm,:].bk.  grid 1024, block 64.
__global__ void k_abqk(const float* __restrict__ A, const float* __restrict__ bq,
                       const float* __restrict__ bk, float* __restrict__ abq,
                       float* __restrict__ abk) {
  int bm = blockIdx.x, t = threadIdx.x;
  float sq = 0.f, sk = 0.f;
  for (int d = t; d < CC; d += 64) {
    float a = A[(size_t)bm*CC + d];
    sq += a*bq[d]; sk += a*bk[d];
  }
  #pragma unroll
  for (int off = 32; off >= 1; off >>= 1) {
    sq += __shfl_xor(sq, off);
    sk += __shfl_xor(sk, off);
  }
  if (t == 0) { abq[bm] = sq; abk[bm] = sk; }
}

// ---------------------------------------------------------------------------
// Aq = A@Wq, Ak = A@Wk. grid (16,32), block 256.
__global__ void k_gemm_nn2(const float* __restrict__ A, const float* __restrict__ Wq,
                           const float* __restrict__ Wk, float* __restrict__ Aq,
                           float* __restrict__ Ak) {
  int t = threadIdx.x;
  int tx = t & 15, ty = t >> 4;
  int r0 = blockIdx.y*32 + ty*2;
  int c0 = blockIdx.x*32 + tx*2;
  float q00=0.f,q01=0.f,q10=0.f,q11=0.f;
  float k00=0.f,k01=0.f,k10=0.f,k11=0.f;
  #pragma unroll 4
  for (int d = 0; d < CC; ++d) {
    float a0 = A[(size_t)r0*CC + d];
    float a1 = A[(size_t)(r0+1)*CC + d];
    float2 wq = *(const float2*)(Wq + (size_t)d*CC + c0);
    float2 wk = *(const float2*)(Wk + (size_t)d*CC + c0);
    q00 += a0*wq.x; q01 += a0*wq.y; q10 += a1*wq.x; q11 += a1*wq.y;
    k00 += a0*wk.x; k01 += a0*wk.y; k10 += a1*wk.x; k11 += a1*wk.y;
  }
  float2 v;
  v.x=q00; v.y=q01; *(float2*)(Aq + (size_t)r0*CC + c0) = v;
  v.x=q10; v.y=q11; *(float2*)(Aq + (size_t)(r0+1)*CC + c0) = v;
  v.x=k00; v.y=k01; *(float2*)(Ak + (size_t)r0*CC + c0) = v;
  v.x=k10; v.y=k11; *(float2*)(Ak + (size_t)(r0+1)*CC + c0) = v;
}

// ---------------------------------------------------------------------------
// FUSED logits: one x pass computes both stage-2 logits L[b,m,n] (pre-softmax)
// and stage-1 probabilities PT[b,n,m] (softmax over m done in-thread).
// grid (8,64), block 128, thread per token. Aq/Ak reads are wave-uniform.
__global__ void k_logits2(const float* __restrict__ x, const float* __restrict__ Aq,
                          const float* __restrict__ Ak, const float* __restrict__ abq,
                          const float* __restrict__ abk, float* __restrict__ L,
                          float* __restrict__ PT) {
  int b = blockIdx.y, t = threadIdx.x;
  int n = blockIdx.x*128 + t;
  const float4* xr  = (const float4*)(x + ((size_t)b*NN + n)*CC);
  const float4* Aq4 = (const float4*)(Aq + (size_t)b*MM*CC);
  const float4* Ak4 = (const float4*)(Ak + (size_t)b*MM*CC);
  float aqa[MM], aka[MM];
  #pragma unroll
  for (int m = 0; m < MM; ++m) { aqa[m] = 0.f; aka[m] = 0.f; }
  for (int c4 = 0; c4 < 128; ++c4) {
    float4 xv = xr[c4];
    #pragma unroll
    for (int m = 0; m < MM; ++m) {
      aqa[m] += dot4(xv, Aq4[m*128 + c4]);
      aka[m] += dot4(xv, Ak4[m*128 + c4]);
    }
  }
  // stage-2 logits out
  #pragma unroll
  for (int m = 0; m < MM; ++m)
    L[((size_t)b*MM + m)*NN + n] = SCALE*(aka[m] + abk[b*MM + m]);
  // stage-1 softmax over m, in-thread
  float mx = -1e30f;
  #pragma unroll
  for (int m = 0; m < MM; ++m) {
    aqa[m] = SCALE*(aqa[m] + abq[b*MM + m]);
    mx = fmaxf(mx, aqa[m]);
  }
  float s = 0.f;
  #pragma unroll
  for (int m = 0; m < MM; ++m) { aqa[m] = expf(aqa[m]-mx); s += aqa[m]; }
  float inv = 1.0f/s;
  float4* PT4 = (float4*)(PT + ((size_t)b*NN + n)*MM);
  #pragma unroll
  for (int j = 0; j < 4; ++j) {
    float4 v = {aqa[j*4+0]*inv, aqa[j*4+1]*inv, aqa[j*4+2]*inv, aqa[j*4+3]*inv};
    PT4[j] = v;
  }
}

// ---------------------------------------------------------------------------
// Row softmax over N=1024, in place. grid 1024 (b*16+m), block 256.
__global__ void k_softmax(float* __restrict__ Lbuf) {
  __shared__ float red[8];
  int row = blockIdx.x, t = threadIdx.x;
  float* Lr = Lbuf + (size_t)row*NN;
  float v[4];
  #pragma unroll
  for (int i = 0; i < 4; ++i) v[i] = Lr[i*256 + t];
  float mx = fmaxf(fmaxf(v[0],v[1]), fmaxf(v[2],v[3]));
  #pragma unroll
  for (int off = 32; off >= 1; off >>= 1) mx = fmaxf(mx, __shfl_xor(mx, off));
  int wid = t >> 6;
  if ((t & 63) == 0) red[wid] = mx;
  __syncthreads();
  mx = fmaxf(fmaxf(red[0],red[1]), fmaxf(red[2],red[3]));
  float e[4], s = 0.f;
  #pragma unroll
  for (int i = 0; i < 4; ++i) { e[i] = expf(v[i]-mx); s += e[i]; }
  #pragma unroll
  for (int off = 32; off >= 1; off >>= 1) s += __shfl_xor(s, off);
  if ((t & 63) == 0) red[4+wid] = s;
  __syncthreads();
  s = red[4]+red[5]+red[6]+red[7];
  float inv = 1.0f/s;
  #pragma unroll
  for (int i = 0; i < 4; ++i) Lr[i*256 + t] = e[i]*inv;
}

// ---------------------------------------------------------------------------
// Spart[ns,b,m,c] = sum over the ns-th 128-token chunk of p*x. No atomics.
// grid (8,64), block 128 (thread = float4 column).
__global__ void k_sacc2(const float* __restrict__ x, const float* __restrict__ Pm,
                        float* __restrict__ Spart) {
  __shared__ float ps[MM*128];
  int ns = blockIdx.x, b = blockIdx.y, t = threadIdx.x;
  #pragma unroll
  for (int k = 0; k < MM; ++k) {
    int i = t + k*128;
    int m = i >> 7, nl = i & 127;
    ps[i] = Pm[((size_t)b*MM + m)*NN + ns*128 + nl];
  }
  __syncthreads();
  float4 acc[MM];
  #pragma unroll
  for (int m = 0; m < MM; ++m) acc[m] = make_float4(0.f,0.f,0.f,0.f);
  const float4* xb = (const float4*)(x + ((size_t)b*NN + ns*128)*CC);
  for (int nl = 0; nl < 128; ++nl) {
    float4 xv = xb[(size_t)nl*128 + t];
    #pragma unroll
    for (int m = 0; m < MM; ++m) {
      float p = ps[m*128 + nl];
      acc[m].x += p*xv.x; acc[m].y += p*xv.y; acc[m].z += p*xv.z; acc[m].w += p*xv.w;
    }
  }
  float4* Sp4 = (float4*)Spart;
  #pragma unroll
  for (int m = 0; m < MM; ++m)
    Sp4[((size_t)ns*NN + b*MM + m)*128 + t] = acc[m];
}

// ---------------------------------------------------------------------------
// S[row,c] = sum_ns Spart[ns,row,c]. grid 512, block 256 (float4 elements).
__global__ void k_sreduce(const float* __restrict__ Spart, float* __restrict__ S) {
  int idx = blockIdx.x*256 + threadIdx.x;   // 0..131071 float4 elements
  const float4* Sp4 = (const float4*)Spart;
  float4 a = {0.f,0.f,0.f,0.f};
  #pragma unroll
  for (int ns = 0; ns < 8; ++ns) {
    float4 v = Sp4[(size_t)ns*NN*128 + idx];
    a.x += v.x; a.y += v.y; a.z += v.z; a.w += v.w;
  }
  ((float4*)S)[idx] = a;
}

// ---------------------------------------------------------------------------
// Combine: out[b,n,:] = sum_m PT[b,n,m]*G[b,m,:]. Pure stream write.
// grid (16,64) (64-token chunks), block 128 (thread = float4 column).
__global__ void k_final2(const float* __restrict__ PT, const float* __restrict__ G,
                         float* __restrict__ out) {
  __shared__ float ps[64*MM];
  int nc = blockIdx.x, b = blockIdx.y, t = threadIdx.x;
  int n0 = nc*64;
  // stage PT[64][16] (1024 floats) coalesced
  {
    const float4* PT4 = (const float4*)(PT + ((size_t)b*NN + n0)*MM);
    float4* ps4 = (float4*)ps;
    ps4[t] = PT4[t];
    ps4[t+128] = PT4[t+128];
  }
  // G rows for this thread's float4 column, kept in registers
  float4 g[MM];
  const float4* G4 = (const float4*)(G + (size_t)b*MM*CC);
  #pragma unroll
  for (int m = 0; m < MM; ++m) g[m] = G4[m*128 + t];
  __syncthreads();
  float4* out4 = (float4*)(out + ((size_t)b*NN + n0)*CC);
  for (int i = 0; i < 64; ++i) {
    float4 o = {0.f,0.f,0.f,0.f};
    #pragma unroll
    for (int m = 0; m < MM; ++m) {
      float p = ps[i*MM + m];
      o.x += p*g[m].x; o.y += p*g[m].y; o.z += p*g[m].z; o.w += p*g[m].w;
    }
    out4[(size_t)i*128 + t] = o;
  }
}

// ---------------------------------------------------------------------------
extern "C" void kernel_launch(void* const* d_in, const int* in_sizes, int n_in,
                              void* d_out, int out_size, void* d_ws, size_t ws_size,
                              hipStream_t stream) {
  (void)in_sizes; (void)n_in; (void)out_size; (void)ws_size;
  const float* x  = (const float*)d_in[0];
  const float* Wq = (const float*)d_in[1];
  const float* bq = (const float*)d_in[2];
  const float* Wk = (const float*)d_in[3];
  const float* bk = (const float*)d_in[4];
  const float* Wv = (const float*)d_in[5];
  const float* bv = (const float*)d_in[6];
  const float* Wo = (const float*)d_in[7];
  const float* bo = (const float*)d_in[8];
  float* out = (float*)d_out;

  float* ws  = (float*)d_ws;
  float* P     = ws;                      // 1024*512
  float* A     = P  + 1024*512;           // 1024*512
  float* Aq    = A  + 1024*512;           // 1024*512
  float* Ak    = Aq + 1024*512;           // 1024*512
  float* abq   = Ak + 1024*512;           // 1024
  float* abk   = abq + 1024;              // 1024
  float* L     = abk + 1024;              // 1024*1024
  float* PT    = L  + 1024*1024;          // 1024*1024  ([b][n][m])
  float* S     = PT + 1024*1024;          // 1024*512
  float* AF    = S  + 1024*512;           // 1024*512
  float* G     = AF + 1024*512;           // 1024*512
  float* Spart = G  + 1024*512;           // 8*1024*512

  k_pool2<<<1024, 256, 0, stream>>>(x, P);
  k_gemm_nt<<<dim3(16,32), 256, 0, stream>>>(P, Wq, bq, A);
  k_abqk<<<1024, 64, 0, stream>>>(A, bq, bk, abq, abk);
  k_gemm_nn2<<<dim3(16,32), 256, 0, stream>>>(A, Wq, Wk, Aq, Ak);
  k_logits2<<<dim3(8,64), 128, 0, stream>>>(x, Aq, Ak, abq, abk, L, PT);
  k_softmax<<<1024, 256, 0, stream>>>(L);
  k_sacc2<<<dim3(8,64), 128, 0, stream>>>(x, L, Spart);
  k_sreduce<<<512, 256, 0, stream>>>(Spart, S);
  k_gemm_nt<<<dim3(16,32), 256, 0, stream>>>(S, Wv, bv, AF);
  k_gemm_nt<<<dim3(16,32), 256, 0, stream>>>(AF, Wo, bo, G);
  k_final2<<<dim3(16,64), 128, 0, stream>>>(PT, G, out);
}

// Round 5
// 760.482 us; speedup vs baseline: 1.1717x; 1.1717x over previous
//
#include <hip/hip_runtime.h>

#define BB 64
#define NN 1024
#define CC 512
#define MM 16
#define SCALE 0.04419417382415922f  // 1/sqrt(512)

__device__ __forceinline__ float dot4(float4 a, float4 b) {
  return a.x*b.x + a.y*b.y + a.z*b.z + a.w*b.w;
}

// ---------------------------------------------------------------------------
// P[b,m,c] = mean over 64 tokens. grid 1024 (b*16+m), block 256 (2-way split).
__global__ void k_pool2(const float* __restrict__ x, float* __restrict__ P) {
  __shared__ float4 tmp[128];
  int blk = blockIdx.x;        // b*16+m
  int t = threadIdx.x;
  int c4 = t & 127, h = t >> 7;
  const float4* base = (const float4*)(x + (size_t)blk * 64 * CC);
  float4 a = {0.f,0.f,0.f,0.f};
  #pragma unroll 8
  for (int i = 0; i < 32; ++i) {
    float4 v = base[(size_t)(h*32 + i)*128 + c4];
    a.x += v.x; a.y += v.y; a.z += v.z; a.w += v.w;
  }
  if (h == 1) tmp[c4] = a;
  __syncthreads();
  if (h == 0) {
    float4 o = tmp[c4];
    const float inv = 1.0f/64.0f;
    float4 r = {(a.x+o.x)*inv, (a.y+o.y)*inv, (a.z+o.z)*inv, (a.w+o.w)*inv};
    ((float4*)P)[(size_t)blk*128 + c4] = r;
  }
}

// ---------------------------------------------------------------------------
// Out[r,d] = sum_c In[r,c]*W[d,c] + bias[d]. grid (16,32), block 256.
__global__ void k_gemm_nt(const float* __restrict__ In, const float* __restrict__ W,
                          const float* __restrict__ bias, float* __restrict__ Out) {
  int t = threadIdx.x;
  int tx = t & 15, ty = t >> 4;
  int r0 = blockIdx.y*32 + ty*2;
  int d0 = blockIdx.x*32 + tx*2;
  const float4* In4 = (const float4*)In;
  const float4* W4  = (const float4*)W;
  float acc00=0.f, acc01=0.f, acc10=0.f, acc11=0.f;
  for (int c4 = 0; c4 < 128; ++c4) {
    float4 a0 = In4[(size_t)r0*128 + c4];
    float4 a1 = In4[(size_t)(r0+1)*128 + c4];
    float4 w0 = W4[(size_t)d0*128 + c4];
    float4 w1 = W4[(size_t)(d0+1)*128 + c4];
    acc00 += dot4(a0,w0); acc01 += dot4(a0,w1);
    acc10 += dot4(a1,w0); acc11 += dot4(a1,w1);
  }
  float b0 = bias[d0], b1 = bias[d0+1];
  float2 o0 = {acc00+b0, acc01+b1};
  float2 o1 = {acc10+b0, acc11+b1};
  *(float2*)(Out + (size_t)r0*CC + d0) = o0;
  *(float2*)(Out + (size_t)(r0+1)*CC + d0) = o1;
}

// ---------------------------------------------------------------------------
// abq[bm] = A[bm,:].bq ; abk[bm] = A[bm,:].bk.  grid 1024, block 64.
__global__ void k_abqk(const float* __restrict__ A, const float* __restrict__ bq,
                       const float* __restrict__ bk, float* __restrict__ abq,
                       float* __restrict__ abk) {
  int bm = blockIdx.x, t = threadIdx.x;
  float sq = 0.f, sk = 0.f;
  for (int d = t; d < CC; d += 64) {
    float a = A[(size_t)bm*CC + d];
    sq += a*bq[d]; sk += a*bk[d];
  }
  #pragma unroll
  for (int off = 32; off >= 1; off >>= 1) {
    sq += __shfl_xor(sq, off);
    sk += __shfl_xor(sk, off);
  }
  if (t == 0) { abq[bm] = sq; abk[bm] = sk; }
}

// ---------------------------------------------------------------------------
// Aq = A@Wq, Ak = A@Wk. grid (16,32), block 256.
__global__ void k_gemm_nn2(const float* __restrict__ A, const float* __restrict__ Wq,
                           const float* __restrict__ Wk, float* __restrict__ Aq,
                           float* __restrict__ Ak) {
  int t = threadIdx.x;
  int tx = t & 15, ty = t >> 4;
  int r0 = blockIdx.y*32 + ty*2;
  int c0 = blockIdx.x*32 + tx*2;
  float q00=0.f,q01=0.f,q10=0.f,q11=0.f;
  float k00=0.f,k01=0.f,k10=0.f,k11=0.f;
  #pragma unroll 4
  for (int d = 0; d < CC; ++d) {
    float a0 = A[(size_t)r0*CC + d];
    float a1 = A[(size_t)(r0+1)*CC + d];
    float2 wq = *(const float2*)(Wq + (size_t)d*CC + c0);
    float2 wk = *(const float2*)(Wk + (size_t)d*CC + c0);
    q00 += a0*wq.x; q01 += a0*wq.y; q10 += a1*wq.x; q11 += a1*wq.y;
    k00 += a0*wk.x; k01 += a0*wk.y; k10 += a1*wk.x; k11 += a1*wk.y;
  }
  float2 v;
  v.x=q00; v.y=q01; *(float2*)(Aq + (size_t)r0*CC + c0) = v;
  v.x=q10; v.y=q11; *(float2*)(Aq + (size_t)(r0+1)*CC + c0) = v;
  v.x=k00; v.y=k01; *(float2*)(Ak + (size_t)r0*CC + c0) = v;
  v.x=k10; v.y=k11; *(float2*)(Ak + (size_t)(r0+1)*CC + c0) = v;
}

// ---------------------------------------------------------------------------
// Fused logits: x staged in LDS (coalesced), A via uniform loads.
// Writes PT[b][n][16] (stage-1 probs), E[b][m][n] = exp(k-logit) unnormalized,
// dpart[ns][b][m] = per-chunk denominators. grid (8,64), block 128.
__global__ __launch_bounds__(128) void k_logits3(
    const float* __restrict__ x, const float* __restrict__ Aq,
    const float* __restrict__ Ak, const float* __restrict__ abq,
    const float* __restrict__ abk, float* __restrict__ PT,
    float* __restrict__ E, float* __restrict__ dpart) {
  __shared__ float4 xs[128*17];   // 34.8 KB, padded rows (17 f4 = 68 floats)
  __shared__ float ds[MM*132];
  __shared__ float ds2[MM*8];
  int b = blockIdx.y, t = threadIdx.x;
  int n0 = blockIdx.x*128;
  int n = n0 + t;
  const float4* Aq4 = (const float4*)(Aq + (size_t)b*MM*CC);
  const float4* Ak4 = (const float4*)(Ak + (size_t)b*MM*CC);
  const float4* xg  = (const float4*)(x + ((size_t)b*NN + n0)*CC);
  float aq[MM], ak[MM];
  #pragma unroll
  for (int m = 0; m < MM; ++m) { aq[m] = 0.f; ak[m] = 0.f; }
  for (int ch = 0; ch < 8; ++ch) {
    __syncthreads();
    // stage x[128 tokens][16 f4] coalesced
    #pragma unroll
    for (int j = 0; j < 16; ++j) {
      int i = j*128 + t;
      int row = i >> 4, col = i & 15;
      xs[row*17 + col] = xg[(size_t)row*128 + ch*16 + col];
    }
    __syncthreads();
    int cb = ch*16;
    #pragma unroll 4
    for (int c4 = 0; c4 < 16; ++c4) {
      float4 xv = xs[t*17 + c4];
      #pragma unroll
      for (int m = 0; m < MM; ++m) {
        aq[m] += dot4(xv, Aq4[m*128 + cb + c4]);   // uniform address
        ak[m] += dot4(xv, Ak4[m*128 + cb + c4]);   // uniform address
      }
    }
  }
  // stage-1 softmax over m, in-thread
  float mx = -1e30f;
  #pragma unroll
  for (int m = 0; m < MM; ++m) {
    aq[m] = SCALE*(aq[m] + abq[b*MM + m]);
    mx = fmaxf(mx, aq[m]);
  }
  float s = 0.f;
  #pragma unroll
  for (int m = 0; m < MM; ++m) { aq[m] = expf(aq[m]-mx); s += aq[m]; }
  float inv = 1.0f/s;
  float4* PT4 = (float4*)(PT + ((size_t)b*NN + n)*MM);
  #pragma unroll
  for (int j = 0; j < 4; ++j) {
    float4 v = {aq[j*4+0]*inv, aq[j*4+1]*inv, aq[j*4+2]*inv, aq[j*4+3]*inv};
    PT4[j] = v;
  }
  // stage-2 unnormalized exp (logits are small; no max-sub needed)
  #pragma unroll
  for (int m = 0; m < MM; ++m) {
    float e = expf(SCALE*(ak[m] + abk[b*MM + m]));
    E[((size_t)b*MM + m)*NN + n] = e;
    ds[m*132 + t] = e;
  }
  __syncthreads();
  {
    int m2 = t >> 3, j2 = t & 7;
    float p = 0.f;
    #pragma unroll
    for (int i = 0; i < 16; ++i) p += ds[m2*132 + j2*16 + i];
    ds2[m2*8 + j2] = p;
  }
  __syncthreads();
  if (t < MM) {
    float d = 0.f;
    #pragma unroll
    for (int j = 0; j < 8; ++j) d += ds2[t*8 + j];
    dpart[((size_t)blockIdx.x*BB + b)*MM + t] = d;
  }
}

// ---------------------------------------------------------------------------
// Spart[ns][b][m][c] = sum over the ns-th 128-token chunk of E*x.
// grid (8,64), block 256 (two 64-token planes, LDS combine).
__global__ __launch_bounds__(256) void k_sacc3(const float* __restrict__ x,
                                               const float* __restrict__ E,
                                               float* __restrict__ Spart) {
  __shared__ float Es[MM*128];     // 8 KB
  __shared__ float4 comb[MM*128];  // 32 KB
  int ns = blockIdx.x, b = blockIdx.y, t = threadIdx.x;
  int col = t & 127, h = t >> 7;
  // stage E chunk [16][128] coalesced
  {
    const float4* E4 = (const float4*)E;
    float4* Es4 = (float4*)Es;
    #pragma unroll
    for (int k = 0; k < 2; ++k) {
      int i = k*256 + t;          // 0..511
      int m = i >> 5, j = i & 31;
      Es4[m*32 + j] = E4[((size_t)b*MM + m)*256 + ns*32 + j];
    }
  }
  __syncthreads();
  float4 acc[MM];
  #pragma unroll
  for (int m = 0; m < MM; ++m) acc[m] = make_float4(0.f,0.f,0.f,0.f);
  const float4* xb = (const float4*)(x + ((size_t)b*NN + ns*128 + h*64)*CC);
  for (int nl = 0; nl < 64; ++nl) {
    float4 xv = xb[(size_t)nl*128 + col];
    #pragma unroll
    for (int m = 0; m < MM; ++m) {
      float p = Es[m*128 + h*64 + nl];   // wave-uniform -> broadcast
      acc[m].x += p*xv.x; acc[m].y += p*xv.y; acc[m].z += p*xv.z; acc[m].w += p*xv.w;
    }
  }
  if (h == 1) {
    #pragma unroll
    for (int m = 0; m < MM; ++m) comb[m*128 + col] = acc[m];
  }
  __syncthreads();
  if (h == 0) {
    float4* Sp4 = (float4*)Spart;
    #pragma unroll
    for (int m = 0; m < MM; ++m) {
      float4 c = comb[m*128 + col];
      float4 r = {acc[m].x+c.x, acc[m].y+c.y, acc[m].z+c.z, acc[m].w+c.w};
      Sp4[(((size_t)ns*BB + b)*MM + m)*128 + col] = r;
    }
  }
}

// ---------------------------------------------------------------------------
// S[row][c] = (sum_ns Spart[ns][row][c]) / (sum_ns dpart[ns][row]).
// grid 512, block 256 over 1024*128 float4 elements.
__global__ void k_sreduce2(const float* __restrict__ Spart,
                           const float* __restrict__ dpart,
                           float* __restrict__ S) {
  int idx = blockIdx.x*256 + threadIdx.x;   // 0..131071
  int row = idx >> 7;                        // b*16+m
  const float4* Sp4 = (const float4*)Spart;
  float4 a = {0.f,0.f,0.f,0.f};
  #pragma unroll
  for (int ns = 0; ns < 8; ++ns) {
    float4 v = Sp4[((size_t)ns*NN + row)*128 + (idx & 127)];
    a.x += v.x; a.y += v.y; a.z += v.z; a.w += v.w;
  }
  float d = 0.f;
  #pragma unroll
  for (int ns = 0; ns < 8; ++ns) d += dpart[(size_t)ns*NN + row];
  float inv = 1.0f/d;
  float4 r = {a.x*inv, a.y*inv, a.z*inv, a.w*inv};
  ((float4*)S)[idx] = r;
}

// ---------------------------------------------------------------------------
// out[b,n,:] = sum_m PT[b,n,m]*G[b,m,:]. PT via uniform loads, G in regs.
// grid (32,64) (32-token chunks), block 128 (thread = float4 column).
__global__ __launch_bounds__(128) void k_final3(const float* __restrict__ PT,
                                                const float* __restrict__ G,
                                                float* __restrict__ out) {
  int nc = blockIdx.x, b = blockIdx.y, t = threadIdx.x;
  float4 g[MM];
  const float4* G4 = (const float4*)(G + (size_t)b*MM*CC);
  #pragma unroll
  for (int m = 0; m < MM; ++m) g[m] = G4[m*128 + t];
  int n0 = nc*32;
  float4* out4 = (float4*)(out + ((size_t)b*NN + n0)*CC);
  const float* pt = PT + ((size_t)b*NN + n0)*MM;   // uniform base
  for (int i = 0; i < 32; ++i) {
    float4 o = {0.f,0.f,0.f,0.f};
    #pragma unroll
    for (int m = 0; m < MM; ++m) {
      float p = pt[i*MM + m];                      // uniform address
      o.x += p*g[m].x; o.y += p*g[m].y; o.z += p*g[m].z; o.w += p*g[m].w;
    }
    out4[(size_t)i*128 + t] = o;
  }
}

// ---------------------------------------------------------------------------
extern "C" void kernel_launch(void* const* d_in, const int* in_sizes, int n_in,
                              void* d_out, int out_size, void* d_ws, size_t ws_size,
                              hipStream_t stream) {
  (void)in_sizes; (void)n_in; (void)out_size; (void)ws_size;
  const float* x  = (const float*)d_in[0];
  const float* Wq = (const float*)d_in[1];
  const float* bq = (const float*)d_in[2];
  const float* Wk = (const float*)d_in[3];
  const float* bk = (const float*)d_in[4];
  const float* Wv = (const float*)d_in[5];
  const float* bv = (const float*)d_in[6];
  const float* Wo = (const float*)d_in[7];
  const float* bo = (const float*)d_in[8];
  float* out = (float*)d_out;

  float* ws  = (float*)d_ws;
  float* P     = ws;                      // 512K floats
  float* A     = P  + 1024*512;
  float* Aq    = A  + 1024*512;
  float* Ak    = Aq + 1024*512;
  float* abq   = Ak + 1024*512;           // 1K
  float* abk   = abq + 1024;              // 1K
  float* PT    = abk + 1024;              // 1M  ([b][n][16])
  float* E     = PT + 1024*1024;          // 1M  ([b][m][n])
  float* dpart = E  + 1024*1024;          // 8K  ([ns][b][m])
  float* S     = dpart + 8*1024;          // 512K
  float* AF    = S  + 1024*512;           // 512K
  float* G     = AF + 1024*512;           // 512K
  float* Spart = G  + 1024*512;           // 4M  ([ns][b][m][512])

  k_pool2<<<1024, 256, 0, stream>>>(x, P);
  k_gemm_nt<<<dim3(16,32), 256, 0, stream>>>(P, Wq, bq, A);
  k_abqk<<<1024, 64, 0, stream>>>(A, bq, bk, abq, abk);
  k_gemm_nn2<<<dim3(16,32), 256, 0, stream>>>(A, Wq, Wk, Aq, Ak);
  k_logits3<<<dim3(8,64), 128, 0, stream>>>(x, Aq, Ak, abq, abk, PT, E, dpart);
  k_sacc3<<<dim3(8,64), 256, 0, stream>>>(x, E, Spart);
  k_sreduce2<<<512, 256, 0, stream>>>(Spart, dpart, S);
  k_gemm_nt<<<dim3(16,32), 256, 0, stream>>>(S, Wv, bv, AF);
  k_gemm_nt<<<dim3(16,32), 256, 0, stream>>>(AF, Wo, bo, G);
  k_final3<<<dim3(32,64), 128, 0, stream>>>(PT, G, out);
}

// Round 6
// 758.976 us; speedup vs baseline: 1.1740x; 1.0020x over previous
//
#include <hip/hip_runtime.h>

#define BB 64
#define NN 1024
#define CC 512
#define MM 16
#define SCALE 0.04419417382415922f  // 1/sqrt(512)

__device__ __forceinline__ float dot4(float4 a, float4 b) {
  return a.x*b.x + a.y*b.y + a.z*b.z + a.w*b.w;
}
__device__ __forceinline__ void fma4(float4& acc, float s, float4 v) {
  acc.x += s*v.x; acc.y += s*v.y; acc.z += s*v.z; acc.w += s*v.w;
}

// ---------------------------------------------------------------------------
// P[b,m,c] = mean over 64 tokens. grid 1024 (b*16+m), block 256 (2-way split).
__global__ void k_pool2(const float* __restrict__ x, float* __restrict__ P) {
  __shared__ float4 tmp[128];
  int blk = blockIdx.x;        // b*16+m
  int t = threadIdx.x;
  int c4 = t & 127, h = t >> 7;
  const float4* base = (const float4*)(x + (size_t)blk * 64 * CC);
  float4 a = {0.f,0.f,0.f,0.f};
  #pragma unroll 8
  for (int i = 0; i < 32; ++i) {
    float4 v = base[(size_t)(h*32 + i)*128 + c4];
    a.x += v.x; a.y += v.y; a.z += v.z; a.w += v.w;
  }
  if (h == 1) tmp[c4] = a;
  __syncthreads();
  if (h == 0) {
    float4 o = tmp[c4];
    const float inv = 1.0f/64.0f;
    float4 r = {(a.x+o.x)*inv, (a.y+o.y)*inv, (a.z+o.z)*inv, (a.w+o.w)*inv};
    ((float4*)P)[(size_t)blk*128 + c4] = r;
  }
}

// ---------------------------------------------------------------------------
// NT Linear: Out[r,d] = sum_c In[r,c]*W[d,c] + bias[d].
// grid (8 dblk, 128 rblk), block 256. 8 rows staged in LDS (broadcast reads),
// W rows per-lane (L1-resident within block: all 4 waves share 64 d-rows).
__global__ __launch_bounds__(256) void k_gemm_nt3(const float* __restrict__ In,
    const float* __restrict__ W, const float* __restrict__ bias,
    float* __restrict__ Out) {
  __shared__ float4 As[8*128];   // 16 KB
  int t = threadIdx.x;
  int rblk = blockIdx.y, dblk = blockIdx.x;
  const float4* In4 = (const float4*)In;
  #pragma unroll
  for (int k = 0; k < 4; ++k) {
    int i = k*256 + t;
    As[i] = In4[(size_t)(rblk*8 + (i>>7))*128 + (i&127)];
  }
  __syncthreads();
  int d = dblk*64 + (t & 63);
  int rr = t >> 6;
  const float4* Wr = (const float4*)W + (size_t)d*128;
  const float4* A0 = &As[(rr*2)*128];
  const float4* A1 = &As[(rr*2+1)*128];
  float acc0 = 0.f, acc1 = 0.f;
  #pragma unroll 4
  for (int c4 = 0; c4 < 128; ++c4) {
    float4 w = Wr[c4];
    acc0 += dot4(A0[c4], w);
    acc1 += dot4(A1[c4], w);
  }
  float bv = bias[d];
  int r0 = rblk*8 + rr*2;
  Out[(size_t)r0*CC + d] = acc0 + bv;
  Out[(size_t)(r0+1)*CC + d] = acc1 + bv;
}

// ---------------------------------------------------------------------------
// abq[bm] = A[bm,:].bq ; abk[bm] = A[bm,:].bk.  grid 1024, block 64.
__global__ void k_abqk(const float* __restrict__ A, const float* __restrict__ bq,
                       const float* __restrict__ bk, float* __restrict__ abq,
                       float* __restrict__ abk) {
  int bm = blockIdx.x, t = threadIdx.x;
  float sq = 0.f, sk = 0.f;
  for (int d = t; d < CC; d += 64) {
    float a = A[(size_t)bm*CC + d];
    sq += a*bq[d]; sk += a*bk[d];
  }
  #pragma unroll
  for (int off = 32; off >= 1; off >>= 1) {
    sq += __shfl_xor(sq, off);
    sk += __shfl_xor(sk, off);
  }
  if (t == 0) { abq[bm] = sq; abk[bm] = sk; }
}

// ---------------------------------------------------------------------------
// NN pair: Aq[r,c] = sum_d A[r,d]*Wq[d,c]; Ak likewise. Lane-per-column
// (coalesced W reads), A rows broadcast from LDS.
// grid (2 cblk, 256 rblk), block 256 (4 rows x 64 f4-cols).
__global__ __launch_bounds__(256) void k_gemm_nn3(const float* __restrict__ A,
    const float* __restrict__ Wq, const float* __restrict__ Wk,
    float* __restrict__ Aq, float* __restrict__ Ak) {
  __shared__ float As[4*512];    // 8 KB
  int t = threadIdx.x;
  int rblk = blockIdx.y, cblk = blockIdx.x;
  const float4* A4 = (const float4*)A;
  float4* As4 = (float4*)As;
  #pragma unroll
  for (int k = 0; k < 2; ++k) {
    int i = k*256 + t;
    As4[i] = A4[(size_t)(rblk*4 + (i>>7))*128 + (i&127)];
  }
  __syncthreads();
  int c4 = cblk*64 + (t & 63);
  int rr = t >> 6;
  const float* Ar = &As[rr*512];
  const float4* Wq4 = (const float4*)Wq;
  const float4* Wk4 = (const float4*)Wk;
  float4 accq = {0.f,0.f,0.f,0.f}, acck = {0.f,0.f,0.f,0.f};
  #pragma unroll 8
  for (int d = 0; d < 512; ++d) {
    float a = Ar[d];
    fma4(accq, a, Wq4[(size_t)d*128 + c4]);
    fma4(acck, a, Wk4[(size_t)d*128 + c4]);
  }
  int row = rblk*4 + rr;
  ((float4*)Aq)[(size_t)row*128 + c4] = accq;
  ((float4*)Ak)[(size_t)row*128 + c4] = acck;
}

// ---------------------------------------------------------------------------
// Partial logits: 4-way C-split. Pq/Pk[cz][b][n][16] = raw partial dots.
// grid (8 nchunk, 64 b, 4 cz), block 128. x staged coalesced in LDS.
__global__ __launch_bounds__(128) void k_logits4(const float* __restrict__ x,
    const float* __restrict__ Aq, const float* __restrict__ Ak,
    float* __restrict__ Pq, float* __restrict__ Pk) {
  __shared__ float4 xs[128*17];  // 34.8 KB padded
  int b = blockIdx.y, t = threadIdx.x, cz = blockIdx.z;
  int n0 = blockIdx.x*128;
  const float4* Aq4 = (const float4*)(Aq + (size_t)b*MM*CC);
  const float4* Ak4 = (const float4*)(Ak + (size_t)b*MM*CC);
  const float4* xg  = (const float4*)(x + ((size_t)b*NN + n0)*CC);
  float aq[MM], ak[MM];
  #pragma unroll
  for (int m = 0; m < MM; ++m) { aq[m] = 0.f; ak[m] = 0.f; }
  for (int ch = 0; ch < 2; ++ch) {
    __syncthreads();
    #pragma unroll
    for (int j = 0; j < 16; ++j) {
      int i = j*128 + t;
      int row = i >> 4, col = i & 15;
      xs[row*17 + col] = xg[(size_t)row*128 + cz*32 + ch*16 + col];
    }
    __syncthreads();
    int cb = cz*32 + ch*16;
    #pragma unroll 4
    for (int c4 = 0; c4 < 16; ++c4) {
      float4 xv = xs[t*17 + c4];
      #pragma unroll
      for (int m = 0; m < MM; ++m) {
        aq[m] += dot4(xv, Aq4[m*128 + cb + c4]);   // uniform -> scalar load
        ak[m] += dot4(xv, Ak4[m*128 + cb + c4]);
      }
    }
  }
  int n = n0 + t;
  float4* Pq4 = (float4*)Pq + (((size_t)cz*BB + b)*NN + n)*4;
  float4* Pk4 = (float4*)Pk + (((size_t)cz*BB + b)*NN + n)*4;
  #pragma unroll
  for (int j = 0; j < 4; ++j) {
    float4 v = {aq[j*4+0], aq[j*4+1], aq[j*4+2], aq[j*4+3]};
    Pq4[j] = v;
    float4 w = {ak[j*4+0], ak[j*4+1], ak[j*4+2], ak[j*4+3]};
    Pk4[j] = w;
  }
}

// ---------------------------------------------------------------------------
// Fused: reduce Pq/Pk partials -> stage-1 softmax -> PT; stage-2 exp -> E (LDS
// only) + dpart; then Spart = E-chunk @ x-chunk. grid (8 ns, 64 b), block 256.
__global__ __launch_bounds__(256) void k_sacc4(const float* __restrict__ x,
    const float* __restrict__ Pq, const float* __restrict__ Pk,
    const float* __restrict__ abq, const float* __restrict__ abk,
    float* __restrict__ PT, float* __restrict__ dpart,
    float* __restrict__ Spart) {
  __shared__ float Es[MM*128];     // 8 KB
  __shared__ float4 comb[MM*128];  // 32 KB
  __shared__ float ds2[128];
  int ns = blockIdx.x, b = blockIdx.y, t = threadIdx.x;
  int n0 = ns*128;
  if (t < 128) {
    // k-side: E = exp(scaled logit), unnormalized (logits provably small)
    int n = n0 + t;
    float4 s[4];
    #pragma unroll
    for (int j = 0; j < 4; ++j) s[j] = make_float4(0.f,0.f,0.f,0.f);
    #pragma unroll
    for (int cz = 0; cz < 4; ++cz) {
      const float4* Pk4 = (const float4*)Pk + (((size_t)cz*BB + b)*NN + n)*4;
      #pragma unroll
      for (int j = 0; j < 4; ++j) {
        float4 v = Pk4[j];
        s[j].x += v.x; s[j].y += v.y; s[j].z += v.z; s[j].w += v.w;
      }
    }
    #pragma unroll
    for (int j = 0; j < 4; ++j) {
      Es[(j*4+0)*128 + t] = expf(SCALE*(s[j].x + abk[b*MM + j*4+0]));
      Es[(j*4+1)*128 + t] = expf(SCALE*(s[j].y + abk[b*MM + j*4+1]));
      Es[(j*4+2)*128 + t] = expf(SCALE*(s[j].z + abk[b*MM + j*4+2]));
      Es[(j*4+3)*128 + t] = expf(SCALE*(s[j].w + abk[b*MM + j*4+3]));
    }
  } else {
    // q-side: in-thread softmax over 16 agents -> PT
    int n = n0 + (t - 128);
    float a[MM];
    #pragma unroll
    for (int m = 0; m < MM; ++m) a[m] = 0.f;
    #pragma unroll
    for (int cz = 0; cz < 4; ++cz) {
      const float4* Pq4 = (const float4*)Pq + (((size_t)cz*BB + b)*NN + n)*4;
      #pragma unroll
      for (int j = 0; j < 4; ++j) {
        float4 v = Pq4[j];
        a[j*4+0] += v.x; a[j*4+1] += v.y; a[j*4+2] += v.z; a[j*4+3] += v.w;
      }
    }
    float mx = -1e30f;
    #pragma unroll
    for (int m = 0; m < MM; ++m) {
      a[m] = SCALE*(a[m] + abq[b*MM + m]);
      mx = fmaxf(mx, a[m]);
    }
    float ssum = 0.f;
    #pragma unroll
    for (int m = 0; m < MM; ++m) { a[m] = expf(a[m]-mx); ssum += a[m]; }
    float inv = 1.0f/ssum;
    float4* PT4 = (float4*)PT + ((size_t)b*NN + n)*4;
    #pragma unroll
    for (int j = 0; j < 4; ++j) {
      float4 v = {a[j*4+0]*inv, a[j*4+1]*inv, a[j*4+2]*inv, a[j*4+3]*inv};
      PT4[j] = v;
    }
  }
  __syncthreads();
  // dpart = per-chunk denominator partials
  if (t < 128) {
    int m = t >> 3, j = t & 7;
    float p = 0.f;
    #pragma unroll
    for (int i = 0; i < 16; ++i) p += Es[m*128 + j*16 + i];
    ds2[t] = p;
  }
  __syncthreads();
  if (t < MM) {
    float dsum = 0.f;
    #pragma unroll
    for (int j = 0; j < 8; ++j) dsum += ds2[t*8 + j];
    dpart[((size_t)ns*BB + b)*MM + t] = dsum;
  }
  // phase B: Spart += E * x over this 128-token chunk
  int col = t & 127, h = t >> 7;
  float4 acc[MM];
  #pragma unroll
  for (int m = 0; m < MM; ++m) acc[m] = make_float4(0.f,0.f,0.f,0.f);
  const float4* xb = (const float4*)(x + ((size_t)b*NN + n0 + h*64)*CC);
  for (int nl = 0; nl < 64; ++nl) {
    float4 xv = xb[(size_t)nl*128 + col];
    #pragma unroll
    for (int m = 0; m < MM; ++m)
      fma4(acc[m], Es[m*128 + h*64 + nl], xv);   // broadcast
  }
  if (h == 1) {
    #pragma unroll
    for (int m = 0; m < MM; ++m) comb[m*128 + col] = acc[m];
  }
  __syncthreads();
  if (h == 0) {
    float4* Sp4 = (float4*)Spart;
    #pragma unroll
    for (int m = 0; m < MM; ++m) {
      float4 c = comb[m*128 + col];
      float4 r = {acc[m].x+c.x, acc[m].y+c.y, acc[m].z+c.z, acc[m].w+c.w};
      Sp4[(((size_t)ns*BB + b)*MM + m)*128 + col] = r;
    }
  }
}

// ---------------------------------------------------------------------------
// S[row][c] = (sum_ns Spart[ns][row][c]) / (sum_ns dpart[ns][row]).
__global__ void k_sreduce2(const float* __restrict__ Spart,
                           const float* __restrict__ dpart,
                           float* __restrict__ S) {
  int idx = blockIdx.x*256 + threadIdx.x;   // 0..131071
  int row = idx >> 7;                        // b*16+m
  const float4* Sp4 = (const float4*)Spart;
  float4 a = {0.f,0.f,0.f,0.f};
  #pragma unroll
  for (int ns = 0; ns < 8; ++ns) {
    float4 v = Sp4[((size_t)ns*NN + row)*128 + (idx & 127)];
    a.x += v.x; a.y += v.y; a.z += v.z; a.w += v.w;
  }
  float d = 0.f;
  #pragma unroll
  for (int ns = 0; ns < 8; ++ns) d += dpart[(size_t)ns*NN + row];
  float inv = 1.0f/d;
  float4 r = {a.x*inv, a.y*inv, a.z*inv, a.w*inv};
  ((float4*)S)[idx] = r;
}

// ---------------------------------------------------------------------------
// out[b,n,:] = sum_m PT[b,n,m]*G[b,m,:]. grid (64,64) (16-token chunks),
// block 128. PT uniform scalar loads, G in regs, coalesced stores.
__global__ __launch_bounds__(128) void k_final4(const float* __restrict__ PT,
                                                const float* __restrict__ G,
                                                float* __restrict__ out) {
  int nc = blockIdx.x, b = blockIdx.y, t = threadIdx.x;
  float4 g[MM];
  const float4* G4 = (const float4*)(G + (size_t)b*MM*CC);
  #pragma unroll
  for (int m = 0; m < MM; ++m) g[m] = G4[m*128 + t];
  int n0 = nc*16;
  float4* out4 = (float4*)(out + ((size_t)b*NN + n0)*CC);
  const float* pt = PT + ((size_t)b*NN + n0)*MM;   // uniform base
  for (int i = 0; i < 16; ++i) {
    float4 o = {0.f,0.f,0.f,0.f};
    #pragma unroll
    for (int m = 0; m < MM; ++m) {
      float p = pt[i*MM + m];
      o.x += p*g[m].x; o.y += p*g[m].y; o.z += p*g[m].z; o.w += p*g[m].w;
    }
    out4[(size_t)i*128 + t] = o;
  }
}

// ---------------------------------------------------------------------------
extern "C" void kernel_launch(void* const* d_in, const int* in_sizes, int n_in,
                              void* d_out, int out_size, void* d_ws, size_t ws_size,
                              hipStream_t stream) {
  (void)in_sizes; (void)n_in; (void)out_size; (void)ws_size;
  const float* x  = (const float*)d_in[0];
  const float* Wq = (const float*)d_in[1];
  const float* bq = (const float*)d_in[2];
  const float* Wk = (const float*)d_in[3];
  const float* bk = (const float*)d_in[4];
  const float* Wv = (const float*)d_in[5];
  const float* bv = (const float*)d_in[6];
  const float* Wo = (const float*)d_in[7];
  const float* bo = (const float*)d_in[8];
  float* out = (float*)d_out;

  float* ws  = (float*)d_ws;
  float* P     = ws;                      // 512K floats
  float* A     = P  + 1024*512;
  float* Aq    = A  + 1024*512;
  float* Ak    = Aq + 1024*512;
  float* abq   = Ak + 1024*512;           // 1K
  float* abk   = abq + 1024;              // 1K
  float* PT    = abk + 1024;              // 1M  ([b][n][16])
  float* dpart = PT + 1024*1024;          // 8K  ([ns][b][m])
  float* S     = dpart + 8*1024;          // 512K
  float* AF    = S  + 1024*512;           // 512K
  float* G     = AF + 1024*512;           // 512K
  float* Spart = G  + 1024*512;           // 4M  ([ns][b][m][512])
  float* Pq    = Spart + 8*1024*512;      // 4M  ([cz][b][n][16])
  float* Pk    = Pq + 4*1024*1024/4*4;    // 4M

  k_pool2<<<1024, 256, 0, stream>>>(x, P);
  k_gemm_nt3<<<dim3(8,128), 256, 0, stream>>>(P, Wq, bq, A);
  k_abqk<<<1024, 64, 0, stream>>>(A, bq, bk, abq, abk);
  k_gemm_nn3<<<dim3(2,256), 256, 0, stream>>>(A, Wq, Wk, Aq, Ak);
  k_logits4<<<dim3(8,64,4), 128, 0, stream>>>(x, Aq, Ak, Pq, Pk);
  k_sacc4<<<dim3(8,64), 256, 0, stream>>>(x, Pq, Pk, abq, abk, PT, dpart, Spart);
  k_sreduce2<<<512, 256, 0, stream>>>(Spart, dpart, S);
  k_gemm_nt3<<<dim3(8,128), 256, 0, stream>>>(S, Wv, bv, AF);
  k_gemm_nt3<<<dim3(8,128), 256, 0, stream>>>(AF, Wo, bo, G);
  k_final4<<<dim3(64,64), 128, 0, stream>>>(PT, G, out);
}

// Round 9
// 741.879 us; speedup vs baseline: 1.2011x; 1.0230x over previous
//
#include <hip/hip_runtime.h>

#define BB 64
#define NN 1024
#define CC 512
#define MM 16
#define SCALE 0.04419417382415922f  // 1/sqrt(512)

__device__ __forceinline__ float dot4(float4 a, float4 b) {
  return a.x*b.x + a.y*b.y + a.z*b.z + a.w*b.w;
}

// ---------------------------------------------------------------------------
// P[b,m,c] = mean over 64 tokens. grid (1024 bm, 2 chalf), block 128.
__global__ __launch_bounds__(128) void k_pool3(const float* __restrict__ x,
                                               float* __restrict__ P) {
  __shared__ float4 tmp[64];
  int bm = blockIdx.x, ch = blockIdx.y, t = threadIdx.x;
  int col = t & 63, p = t >> 6;
  const float4* base = (const float4*)(x + (size_t)bm*64*CC) + ch*64;
  float4 a = {0.f,0.f,0.f,0.f};
  #pragma unroll 8
  for (int i = 0; i < 32; ++i) {
    float4 v = base[(size_t)(p*32 + i)*128 + col];
    a.x += v.x; a.y += v.y; a.z += v.z; a.w += v.w;
  }
  if (p == 1) tmp[col] = a;
  __syncthreads();
  if (p == 0) {
    float4 o = tmp[col];
    const float inv = 1.0f/64.0f;
    float4 r = {(a.x+o.x)*inv, (a.y+o.y)*inv, (a.z+o.z)*inv, (a.w+o.w)*inv};
    ((float4*)P)[(size_t)bm*128 + ch*64 + col] = r;
  }
}

// ---------------------------------------------------------------------------
// NT Linear with K-split: Out[r,d] += sum_{c in kz} In[r,c]*W[d,c] (+bias @kz0)
// Out MUST be zeroed first. grid (8 dblk, 16 rblk, 4 kz), block 256.
// 64x64 tile, LDS-staged both operands, 4x4 micro-tile.
__global__ __launch_bounds__(256) void k_gemm_nt4(const float* __restrict__ In,
    const float* __restrict__ W, const float* __restrict__ bias,
    float* __restrict__ Out) {
  __shared__ float Is[64*36];   // 9 KB, padded rows (36 floats)
  __shared__ float Ws[64*36];
  int t = threadIdx.x;
  int dblk = blockIdx.x, rblk = blockIdx.y, kz = blockIdx.z;
  int td = t & 15, tr = t >> 4;
  float acc[4][4];
  #pragma unroll
  for (int i = 0; i < 4; ++i)
    #pragma unroll
    for (int j = 0; j < 4; ++j) acc[i][j] = 0.f;
  const float4* In4 = (const float4*)In;
  const float4* W4  = (const float4*)W;
  for (int chk = 0; chk < 4; ++chk) {
    int kc = kz*32 + chk*8;    // f4 offset in K
    __syncthreads();
    #pragma unroll
    for (int p = 0; p < 2; ++p) {
      int i = p*256 + t;       // 0..511
      int r = i >> 3, cc = i & 7;
      float4 v = In4[(size_t)(rblk*64 + r)*128 + kc + cc];
      *(float4*)&Is[r*36 + cc*4] = v;
      float4 w = W4[(size_t)(dblk*64 + r)*128 + kc + cc];
      *(float4*)&Ws[r*36 + cc*4] = w;
    }
    __syncthreads();
    #pragma unroll
    for (int cc = 0; cc < 8; ++cc) {
      float4 a0 = *(float4*)&Is[(tr*4+0)*36 + cc*4];
      float4 a1 = *(float4*)&Is[(tr*4+1)*36 + cc*4];
      float4 a2 = *(float4*)&Is[(tr*4+2)*36 + cc*4];
      float4 a3 = *(float4*)&Is[(tr*4+3)*36 + cc*4];
      float4 w0 = *(float4*)&Ws[(td*4+0)*36 + cc*4];
      float4 w1 = *(float4*)&Ws[(td*4+1)*36 + cc*4];
      float4 w2 = *(float4*)&Ws[(td*4+2)*36 + cc*4];
      float4 w3 = *(float4*)&Ws[(td*4+3)*36 + cc*4];
      acc[0][0] += dot4(a0,w0); acc[0][1] += dot4(a0,w1);
      acc[0][2] += dot4(a0,w2); acc[0][3] += dot4(a0,w3);
      acc[1][0] += dot4(a1,w0); acc[1][1] += dot4(a1,w1);
      acc[1][2] += dot4(a1,w2); acc[1][3] += dot4(a1,w3);
      acc[2][0] += dot4(a2,w0); acc[2][1] += dot4(a2,w1);
      acc[2][2] += dot4(a2,w2); acc[2][3] += dot4(a2,w3);
      acc[3][0] += dot4(a3,w0); acc[3][1] += dot4(a3,w1);
      acc[3][2] += dot4(a3,w2); acc[3][3] += dot4(a3,w3);
    }
  }
  int r0 = rblk*64 + tr*4, d0 = dblk*64 + td*4;
  if (kz == 0) {
    #pragma unroll
    for (int j = 0; j < 4; ++j) {
      float bj = bias[d0+j];
      #pragma unroll
      for (int i = 0; i < 4; ++i) acc[i][j] += bj;
    }
  }
  #pragma unroll
  for (int i = 0; i < 4; ++i)
    #pragma unroll
    for (int j = 0; j < 4; ++j)
      atomicAdd(&Out[(size_t)(r0+i)*CC + d0 + j], acc[i][j]);
}

// ---------------------------------------------------------------------------
// abq[bm] = A[bm,:].bq ; abk[bm] = A[bm,:].bk.  grid 1024, block 64.
__global__ void k_abqk(const float* __restrict__ A, const float* __restrict__ bq,
                       const float* __restrict__ bk, float* __restrict__ abq,
                       float* __restrict__ abk) {
  int bm = blockIdx.x, t = threadIdx.x;
  float sq = 0.f, sk = 0.f;
  for (int d = t; d < CC; d += 64) {
    float a = A[(size_t)bm*CC + d];
    sq += a*bq[d]; sk += a*bk[d];
  }
  #pragma unroll
  for (int off = 32; off >= 1; off >>= 1) {
    sq += __shfl_xor(sq, off);
    sk += __shfl_xor(sk, off);
  }
  if (t == 0) { abq[bm] = sq; abk[bm] = sk; }
}

// ---------------------------------------------------------------------------
// NN pair: Aq[r,c] = sum_d A[r,d]*Wq[d,c]; Ak likewise. Lane-per-column,
// A rows broadcast from LDS. grid (2 cblk, 256 rblk), block 256.
__global__ __launch_bounds__(256) void k_gemm_nn3(const float* __restrict__ A,
    const float* __restrict__ Wq, const float* __restrict__ Wk,
    float* __restrict__ Aq, float* __restrict__ Ak) {
  __shared__ float As[4*512];    // 8 KB
  int t = threadIdx.x;
  int rblk = blockIdx.y, cblk = blockIdx.x;
  const float4* A4 = (const float4*)A;
  float4* As4 = (float4*)As;
  #pragma unroll
  for (int k = 0; k < 2; ++k) {
    int i = k*256 + t;
    As4[i] = A4[(size_t)(rblk*4 + (i>>7))*128 + (i&127)];
  }
  __syncthreads();
  int c4 = cblk*64 + (t & 63);
  int rr = t >> 6;
  const float* Ar = &As[rr*512];
  const float4* Wq4 = (const float4*)Wq;
  const float4* Wk4 = (const float4*)Wk;
  float4 accq = {0.f,0.f,0.f,0.f}, acck = {0.f,0.f,0.f,0.f};
  #pragma unroll 8
  for (int d = 0; d < 512; ++d) {
    float a = Ar[d];
    float4 wq = Wq4[(size_t)d*128 + c4];
    float4 wk = Wk4[(size_t)d*128 + c4];
    accq.x += a*wq.x; accq.y += a*wq.y; accq.z += a*wq.z; accq.w += a*wq.w;
    acck.x += a*wk.x; acck.y += a*wk.y; acck.z += a*wk.z; acck.w += a*wk.w;
  }
  int row = rblk*4 + rr;
  ((float4*)Aq)[(size_t)row*128 + c4] = accq;
  ((float4*)Ak)[(size_t)row*128 + c4] = acck;
}

// ---------------------------------------------------------------------------
// MEGA: per (b, 64-token chunk): transposed-dot logits (no LDS staging,
// shuffle-reduced), stage-1 softmax -> PT, stage-2 exp -> Es (LDS) + dpart,
// then S-partial = Es^T @ x-chunk (x re-read, L2-hot).
// grid (16 ns, 64 b), block 256.
__global__ __launch_bounds__(256) void k_mega(const float* __restrict__ x,
    const float* __restrict__ Aq, const float* __restrict__ Ak,
    const float* __restrict__ abq, const float* __restrict__ abk,
    float* __restrict__ PT, float* __restrict__ dpart,
    float* __restrict__ Spart) {
  __shared__ float Es[64*16];    // [tok][m], 4 KB
  __shared__ float ds2[128];
  int ns = blockIdx.x, b = blockIdx.y, t = threadIdx.x;
  int n0 = ns*64;
  int ci = t & 15, tw = t >> 4;     // 16 token-slots x 16 c-residues
  const float4* Aq4 = (const float4*)(Aq + (size_t)b*MM*CC);
  const float4* Ak4 = (const float4*)(Ak + (size_t)b*MM*CC);
  // ---- phase A: logits for 64 tokens in 4 passes of 16
  for (int pass = 0; pass < 4; ++pass) {
    int tok = pass*16 + tw;
    int n = n0 + tok;
    const float4* xr = (const float4*)(x + ((size_t)b*NN + n)*CC);
    float aq[MM], ak[MM];
    #pragma unroll
    for (int m = 0; m < MM; ++m) { aq[m] = 0.f; ak[m] = 0.f; }
    #pragma unroll 4
    for (int k = 0; k < 8; ++k) {
      float4 xv = xr[k*16 + ci];
      #pragma unroll
      for (int m = 0; m < MM; ++m) {
        aq[m] += dot4(xv, Aq4[m*128 + k*16 + ci]);
        ak[m] += dot4(xv, Ak4[m*128 + k*16 + ci]);
      }
    }
    // reduce over the 16 c-residue lanes (butterfly within 16-lane groups)
    #pragma unroll
    for (int off = 1; off < 16; off <<= 1) {
      #pragma unroll
      for (int m = 0; m < MM; ++m) {
        aq[m] += __shfl_xor(aq[m], off);
        ak[m] += __shfl_xor(ak[m], off);
      }
    }
    if (ci == 0) {
      // stage-1 softmax over m -> PT
      float mx = -1e30f;
      #pragma unroll
      for (int m = 0; m < MM; ++m) {
        aq[m] = SCALE*(aq[m] + abq[b*MM + m]);
        mx = fmaxf(mx, aq[m]);
      }
      float s = 0.f;
      #pragma unroll
      for (int m = 0; m < MM; ++m) { aq[m] = expf(aq[m]-mx); s += aq[m]; }
      float inv = 1.0f/s;
      float4* PT4 = (float4*)(PT + ((size_t)b*NN + n)*MM);
      #pragma unroll
      for (int j = 0; j < 4; ++j) {
        float4 v = {aq[j*4+0]*inv, aq[j*4+1]*inv, aq[j*4+2]*inv, aq[j*4+3]*inv};
        PT4[j] = v;
      }
      // stage-2 unnormalized exp (logits provably small) -> Es
      float e[MM];
      #pragma unroll
      for (int m = 0; m < MM; ++m)
        e[m] = expf(SCALE*(ak[m] + abk[b*MM + m]));
      float4* er = (float4*)&Es[tok*MM];
      #pragma unroll
      for (int j = 0; j < 4; ++j) {
        float4 v = {e[j*4+0], e[j*4+1], e[j*4+2], e[j*4+3]};
        er[j] = v;
      }
    }
  }
  __syncthreads();
  // ---- dpart = per-chunk denominators
  if (t < 128) {
    int m = t >> 3, j = t & 7;
    float p = 0.f;
    #pragma unroll
    for (int i = 0; i < 8; ++i) p += Es[(j*8 + i)*MM + m];
    ds2[m*8 + j] = p;
  }
  __syncthreads();
  if (t < MM) {
    float d = 0.f;
    #pragma unroll
    for (int j = 0; j < 8; ++j) d += ds2[t*8 + j];
    dpart[(size_t)ns*NN + b*MM + t] = d;
  }
  // ---- phase B: Spart[ns][b][m][c] = sum_n Es[n][m] * x[n][c] (x L2-hot)
  int c2 = t;                      // float2 column 0..255
  float2 acc[MM];
  #pragma unroll
  for (int m = 0; m < MM; ++m) acc[m] = make_float2(0.f, 0.f);
  const float2* xb = (const float2*)(x + ((size_t)b*NN + n0)*CC);
  #pragma unroll 4
  for (int nl = 0; nl < 64; ++nl) {
    float2 xv = xb[(size_t)nl*256 + c2];
    #pragma unroll
    for (int m = 0; m < MM; ++m) {
      float e = Es[nl*MM + m];     // uniform -> broadcast
      acc[m].x += e*xv.x; acc[m].y += e*xv.y;
    }
  }
  float2* Sp2 = (float2*)Spart;
  #pragma unroll
  for (int m = 0; m < MM; ++m)
    Sp2[(((size_t)ns*BB + b)*MM + m)*256 + c2] = acc[m];
}

// ---------------------------------------------------------------------------
// S[row][c] = (sum_ns Spart[ns][row][c]) / (sum_ns dpart[ns][row]).
// grid 512, block 256 over 1024*128 float4.
__global__ void k_sreduce3(const float* __restrict__ Spart,
                           const float* __restrict__ dpart,
                           float* __restrict__ S) {
  int idx = blockIdx.x*256 + threadIdx.x;   // 0..131071
  int row = idx >> 7;                        // b*16+m
  const float4* Sp4 = (const float4*)Spart;
  float4 a = {0.f,0.f,0.f,0.f};
  #pragma unroll
  for (int ns = 0; ns < 16; ++ns) {
    float4 v = Sp4[((size_t)ns*NN + row)*128 + (idx & 127)];
    a.x += v.x; a.y += v.y; a.z += v.z; a.w += v.w;
  }
  float d = 0.f;
  #pragma unroll
  for (int ns = 0; ns < 16; ++ns) d += dpart[(size_t)ns*NN + row];
  float inv = 1.0f/d;
  float4 r = {a.x*inv, a.y*inv, a.z*inv, a.w*inv};
  ((float4*)S)[idx] = r;
}

// ---------------------------------------------------------------------------
// out[b,n,:] = sum_m PT[b,n,m]*G[b,m,:]. grid (32 nc, 64 b), block 256
// (2 token-planes x 128 f4-cols). G in regs, PT in 2 KB LDS.
__global__ __launch_bounds__(256) void k_final5(const float* __restrict__ PT,
                                                const float* __restrict__ G,
                                                float* __restrict__ out) {
  __shared__ float ps[32*MM];    // 2 KB
  int nc = blockIdx.x, b = blockIdx.y, t = threadIdx.x;
  int col = t & 127, h = t >> 7;
  int n0 = nc*32;
  if (t < 128)
    ((float4*)ps)[t] = ((const float4*)(PT + ((size_t)b*NN + n0)*MM))[t];
  float4 g[MM];
  const float4* G4 = (const float4*)(G + (size_t)b*MM*CC);
  #pragma unroll
  for (int m = 0; m < MM; ++m) g[m] = G4[m*128 + col];
  __syncthreads();
  float4* out4 = (float4*)(out + ((size_t)b*NN + n0 + h*16)*CC);
  for (int i = 0; i < 16; ++i) {
    float4 o = {0.f,0.f,0.f,0.f};
    #pragma unroll
    for (int m = 0; m < MM; ++m) {
      float p = ps[(h*16 + i)*MM + m];
      o.x += p*g[m].x; o.y += p*g[m].y; o.z += p*g[m].z; o.w += p*g[m].w;
    }
    out4[(size_t)i*128 + col] = o;
  }
}

// ---------------------------------------------------------------------------
extern "C" void kernel_launch(void* const* d_in, const int* in_sizes, int n_in,
                              void* d_out, int out_size, void* d_ws, size_t ws_size,
                              hipStream_t stream) {
  (void)in_sizes; (void)n_in; (void)out_size; (void)ws_size;
  const float* x  = (const float*)d_in[0];
  const float* Wq = (const float*)d_in[1];
  const float* bq = (const float*)d_in[2];
  const float* Wk = (const float*)d_in[3];
  const float* bk = (const float*)d_in[4];
  const float* Wv = (const float*)d_in[5];
  const float* bv = (const float*)d_in[6];
  const float* Wo = (const float*)d_in[7];
  const float* bo = (const float*)d_in[8];
  float* out = (float*)d_out;

  float* ws  = (float*)d_ws;
  float* P     = ws;                      // 512K floats
  float* A     = P  + 1024*512;           // 512K
  float* Aq    = A  + 1024*512;           // 512K
  float* Ak    = Aq + 1024*512;           // 512K
  float* abq   = Ak + 1024*512;           // 1K
  float* abk   = abq + 1024;              // 1K
  float* PT    = abk + 1024;              // 1M  ([b][n][16])
  float* dpart = PT + 1024*1024;          // 16K ([ns][b][m])
  float* S     = dpart + 16*1024;         // 512K
  float* AF    = S  + 1024*512;           // 512K
  float* G     = AF + 1024*512;           // 512K
  float* Spart = G  + 1024*512;           // 8M  ([ns][b][m][512])

  hipMemsetAsync(A,  0, (size_t)1024*512*sizeof(float), stream);
  hipMemsetAsync(AF, 0, (size_t)1024*512*sizeof(float), stream);
  hipMemsetAsync(G,  0, (size_t)1024*512*sizeof(float), stream);

  k_pool3<<<dim3(1024,2), 128, 0, stream>>>(x, P);
  k_gemm_nt4<<<dim3(8,16,4), 256, 0, stream>>>(P, Wq, bq, A);
  k_abqk<<<1024, 64, 0, stream>>>(A, bq, bk, abq, abk);
  k_gemm_nn3<<<dim3(2,256), 256, 0, stream>>>(A, Wq, Wk, Aq, Ak);
  k_mega<<<dim3(16,64), 256, 0, stream>>>(x, Aq, Ak, abq, abk, PT, dpart, Spart);
  k_sreduce3<<<512, 256, 0, stream>>>(Spart, dpart, S);
  k_gemm_nt4<<<dim3(8,16,4), 256, 0, stream>>>(S, Wv, bv, AF);
  k_gemm_nt4<<<dim3(8,16,4), 256, 0, stream>>>(AF, Wo, bo, G);
  k_final5<<<dim3(32,64), 256, 0, stream>>>(PT, G, out);
}

// Round 11
// 639.904 us; speedup vs baseline: 1.3925x; 1.1594x over previous
//
#include <hip/hip_runtime.h>

#define BB 64
#define NN 1024
#define CC 512
#define MM 16
#define SCALE 0.04419417382415922f  // 1/sqrt(512)

__device__ __forceinline__ float dot4(float4 a, float4 b) {
  return a.x*b.x + a.y*b.y + a.z*b.z + a.w*b.w;
}

// ---------------------------------------------------------------------------
// P[b,m,c] = mean over 64 tokens. grid (1024 bm, 2 chalf), block 128.
__global__ __launch_bounds__(128) void k_pool3(const float* __restrict__ x,
                                               float* __restrict__ P) {
  __shared__ float4 tmp[64];
  int bm = blockIdx.x, ch = blockIdx.y, t = threadIdx.x;
  int col = t & 63, p = t >> 6;
  const float4* base = (const float4*)(x + (size_t)bm*64*CC) + ch*64;
  float4 a = {0.f,0.f,0.f,0.f};
  #pragma unroll 8
  for (int i = 0; i < 32; ++i) {
    float4 v = base[(size_t)(p*32 + i)*128 + col];
    a.x += v.x; a.y += v.y; a.z += v.z; a.w += v.w;
  }
  if (p == 1) tmp[col] = a;
  __syncthreads();
  if (p == 0) {
    float4 o = tmp[col];
    const float inv = 1.0f/64.0f;
    float4 r = {(a.x+o.x)*inv, (a.y+o.y)*inv, (a.z+o.z)*inv, (a.w+o.w)*inv};
    ((float4*)P)[(size_t)bm*128 + ch*64 + col] = r;
  }
}

// ---------------------------------------------------------------------------
// NT Linear with K-split: Out[r,d] += sum_{c in kz} In[r,c]*W[d,c] (+bias @kz0)
// Out MUST be zeroed first. grid (8 dblk, 16 rblk, 4 kz), block 256.
__global__ __launch_bounds__(256) void k_gemm_nt4(const float* __restrict__ In,
    const float* __restrict__ W, const float* __restrict__ bias,
    float* __restrict__ Out) {
  __shared__ float Is[64*36];   // 9 KB, padded rows (36 floats)
  __shared__ float Ws[64*36];
  int t = threadIdx.x;
  int dblk = blockIdx.x, rblk = blockIdx.y, kz = blockIdx.z;
  int td = t & 15, tr = t >> 4;
  float acc[4][4];
  #pragma unroll
  for (int i = 0; i < 4; ++i)
    #pragma unroll
    for (int j = 0; j < 4; ++j) acc[i][j] = 0.f;
  const float4* In4 = (const float4*)In;
  const float4* W4  = (const float4*)W;
  for (int chk = 0; chk < 4; ++chk) {
    int kc = kz*32 + chk*8;    // f4 offset in K
    __syncthreads();
    #pragma unroll
    for (int p = 0; p < 2; ++p) {
      int i = p*256 + t;       // 0..511
      int r = i >> 3, cc = i & 7;
      float4 v = In4[(size_t)(rblk*64 + r)*128 + kc + cc];
      *(float4*)&Is[r*36 + cc*4] = v;
      float4 w = W4[(size_t)(dblk*64 + r)*128 + kc + cc];
      *(float4*)&Ws[r*36 + cc*4] = w;
    }
    __syncthreads();
    #pragma unroll
    for (int cc = 0; cc < 8; ++cc) {
      float4 a0 = *(float4*)&Is[(tr*4+0)*36 + cc*4];
      float4 a1 = *(float4*)&Is[(tr*4+1)*36 + cc*4];
      float4 a2 = *(float4*)&Is[(tr*4+2)*36 + cc*4];
      float4 a3 = *(float4*)&Is[(tr*4+3)*36 + cc*4];
      float4 w0 = *(float4*)&Ws[(td*4+0)*36 + cc*4];
      float4 w1 = *(float4*)&Ws[(td*4+1)*36 + cc*4];
      float4 w2 = *(float4*)&Ws[(td*4+2)*36 + cc*4];
      float4 w3 = *(float4*)&Ws[(td*4+3)*36 + cc*4];
      acc[0][0] += dot4(a0,w0); acc[0][1] += dot4(a0,w1);
      acc[0][2] += dot4(a0,w2); acc[0][3] += dot4(a0,w3);
      acc[1][0] += dot4(a1,w0); acc[1][1] += dot4(a1,w1);
      acc[1][2] += dot4(a1,w2); acc[1][3] += dot4(a1,w3);
      acc[2][0] += dot4(a2,w0); acc[2][1] += dot4(a2,w1);
      acc[2][2] += dot4(a2,w2); acc[2][3] += dot4(a2,w3);
      acc[3][0] += dot4(a3,w0); acc[3][1] += dot4(a3,w1);
      acc[3][2] += dot4(a3,w2); acc[3][3] += dot4(a3,w3);
    }
  }
  int r0 = rblk*64 + tr*4, d0 = dblk*64 + td*4;
  if (kz == 0) {
    #pragma unroll
    for (int j = 0; j < 4; ++j) {
      float bj = bias[d0+j];
      #pragma unroll
      for (int i = 0; i < 4; ++i) acc[i][j] += bj;
    }
  }
  #pragma unroll
  for (int i = 0; i < 4; ++i)
    #pragma unroll
    for (int j = 0; j < 4; ++j)
      atomicAdd(&Out[(size_t)(r0+i)*CC + d0 + j], acc[i][j]);
}

// ---------------------------------------------------------------------------
// NN pair + abqk fused: Aq = A@Wq, Ak = A@Wk; cblk==0 wave0 also computes
// abq/abk for its 4 rows. grid (2 cblk, 256 rblk), block 256.
__global__ __launch_bounds__(256) void k_gemm_nn3(const float* __restrict__ A,
    const float* __restrict__ Wq, const float* __restrict__ Wk,
    const float* __restrict__ bq, const float* __restrict__ bk,
    float* __restrict__ Aq, float* __restrict__ Ak,
    float* __restrict__ abq, float* __restrict__ abk) {
  __shared__ float As[4*512];    // 8 KB
  int t = threadIdx.x;
  int rblk = blockIdx.y, cblk = blockIdx.x;
  const float4* A4 = (const float4*)A;
  float4* As4 = (float4*)As;
  #pragma unroll
  for (int k = 0; k < 2; ++k) {
    int i = k*256 + t;
    As4[i] = A4[(size_t)(rblk*4 + (i>>7))*128 + (i&127)];
  }
  __syncthreads();
  // fused abq/abk (wave 0 of cblk==0 blocks)
  if (cblk == 0 && t < 64) {
    int row = t >> 4, seg = t & 15;
    float sq = 0.f, sk = 0.f;
    #pragma unroll 8
    for (int i = 0; i < 32; ++i) {
      float a = As[row*512 + seg*32 + i];
      sq += a*bq[seg*32 + i];
      sk += a*bk[seg*32 + i];
    }
    #pragma unroll
    for (int off = 1; off < 16; off <<= 1) {
      sq += __shfl_xor(sq, off);
      sk += __shfl_xor(sk, off);
    }
    if (seg == 0) { abq[rblk*4 + row] = sq; abk[rblk*4 + row] = sk; }
  }
  int c4 = cblk*64 + (t & 63);
  int rr = t >> 6;
  const float* Ar = &As[rr*512];
  const float4* Wq4 = (const float4*)Wq;
  const float4* Wk4 = (const float4*)Wk;
  float4 accq = {0.f,0.f,0.f,0.f}, acck = {0.f,0.f,0.f,0.f};
  #pragma unroll 8
  for (int d = 0; d < 512; ++d) {
    float a = Ar[d];
    float4 wq = Wq4[(size_t)d*128 + c4];
    float4 wk = Wk4[(size_t)d*128 + c4];
    accq.x += a*wq.x; accq.y += a*wq.y; accq.z += a*wq.z; accq.w += a*wq.w;
    acck.x += a*wk.x; acck.y += a*wk.y; acck.z += a*wk.z; acck.w += a*wk.w;
  }
  int row = rblk*4 + rr;
  ((float4*)Aq)[(size_t)row*128 + c4] = accq;
  ((float4*)Ak)[(size_t)row*128 + c4] = acck;
}

// ---------------------------------------------------------------------------
// MEGA: per (b, 64-token chunk), 512 threads (8 waves), <=64 VGPR forced.
// Phase A: transposed-dot logits (32 tok-slots x 16 ci, 2 passes), softmax ->
// Ps/Es in LDS (padded rows); coalesced PT write; dpart.
// Phase B: Spart[ns*2+h] = Es^T @ x-half-chunk (x L2-hot).
// grid (16 ns, 64 b), block 512.
__global__ __launch_bounds__(512, 8) void k_mega(const float* __restrict__ x,
    const float* __restrict__ Aq, const float* __restrict__ Ak,
    const float* __restrict__ abq, const float* __restrict__ abk,
    float* __restrict__ PT, float* __restrict__ dpart,
    float* __restrict__ Spart) {
  __shared__ float Es[64*20];    // [tok][m], padded to 20 (bank spread)
  __shared__ float Ps[64*20];
  __shared__ float ds2[128];
  int ns = blockIdx.x, b = blockIdx.y, t = threadIdx.x;
  int n0 = ns*64;
  int ci = t & 15, tw = t >> 4;     // 32 token-slots x 16 c-residues
  const float4* Aq4 = (const float4*)(Aq + (size_t)b*MM*CC);
  const float4* Ak4 = (const float4*)(Ak + (size_t)b*MM*CC);
  // ---- phase A: logits for 64 tokens in 2 passes of 32
  for (int pass = 0; pass < 2; ++pass) {
    int tok = pass*32 + tw;
    int n = n0 + tok;
    const float4* xr = (const float4*)(x + ((size_t)b*NN + n)*CC);
    float aq[MM], ak[MM];
    #pragma unroll
    for (int m = 0; m < MM; ++m) { aq[m] = 0.f; ak[m] = 0.f; }
    #pragma unroll 4
    for (int k = 0; k < 8; ++k) {
      float4 xv = xr[k*16 + ci];
      #pragma unroll
      for (int m = 0; m < MM; ++m) {
        aq[m] += dot4(xv, Aq4[m*128 + k*16 + ci]);
        ak[m] += dot4(xv, Ak4[m*128 + k*16 + ci]);
      }
    }
    #pragma unroll
    for (int off = 1; off < 16; off <<= 1) {
      #pragma unroll
      for (int m = 0; m < MM; ++m) {
        aq[m] += __shfl_xor(aq[m], off);
        ak[m] += __shfl_xor(ak[m], off);
      }
    }
    if (ci == 0) {
      float mx = -1e30f;
      #pragma unroll
      for (int m = 0; m < MM; ++m) {
        aq[m] = SCALE*(aq[m] + abq[b*MM + m]);
        mx = fmaxf(mx, aq[m]);
      }
      float s = 0.f;
      #pragma unroll
      for (int m = 0; m < MM; ++m) { aq[m] = expf(aq[m]-mx); s += aq[m]; }
      float inv = 1.0f/s;
      #pragma unroll
      for (int m = 0; m < MM; ++m) Ps[tok*20 + m] = aq[m]*inv;
      #pragma unroll
      for (int m = 0; m < MM; ++m)
        Es[tok*20 + m] = expf(SCALE*(ak[m] + abk[b*MM + m]));
    }
  }
  __syncthreads();
  // ---- coalesced PT write (256 threads, one f4 each)
  if (t < 256) {
    int tok = t >> 2, q = t & 3;
    float4 v = {Ps[tok*20 + q*4+0], Ps[tok*20 + q*4+1],
                Ps[tok*20 + q*4+2], Ps[tok*20 + q*4+3]};
    ((float4*)PT)[((size_t)b*NN + n0 + tok)*4 + q] = v;
  }
  // ---- dpart = per-chunk denominators
  if (t < 128) {
    int m = t >> 3, j = t & 7;
    float p = 0.f;
    #pragma unroll
    for (int i = 0; i < 8; ++i) p += Es[(j*8 + i)*20 + m];
    ds2[m*8 + j] = p;
  }
  __syncthreads();
  if (t < MM) {
    float d = 0.f;
    #pragma unroll
    for (int j = 0; j < 8; ++j) d += ds2[t*8 + j];
    dpart[(size_t)ns*NN + b*MM + t] = d;
  }
  // ---- phase B: half-block h handles 32 tokens; Spart[ns*2+h]
  int c2 = t & 255, h = t >> 8;      // h is wave-uniform
  float2 acc[MM];
  #pragma unroll
  for (int m = 0; m < MM; ++m) acc[m] = make_float2(0.f, 0.f);
  const float2* xb = (const float2*)(x + ((size_t)b*NN + n0 + h*32)*CC);
  #pragma unroll 2
  for (int nl = 0; nl < 32; ++nl) {
    float2 xv = xb[(size_t)nl*256 + c2];
    const float* er = &Es[(h*32 + nl)*20];
    float4 e0 = *(const float4*)&er[0];
    float4 e1 = *(const float4*)&er[4];
    float4 e2 = *(const float4*)&er[8];
    float4 e3 = *(const float4*)&er[12];
    acc[0].x += e0.x*xv.x; acc[0].y += e0.x*xv.y;
    acc[1].x += e0.y*xv.x; acc[1].y += e0.y*xv.y;
    acc[2].x += e0.z*xv.x; acc[2].y += e0.z*xv.y;
    acc[3].x += e0.w*xv.x; acc[3].y += e0.w*xv.y;
    acc[4].x += e1.x*xv.x; acc[4].y += e1.x*xv.y;
    acc[5].x += e1.y*xv.x; acc[5].y += e1.y*xv.y;
    acc[6].x += e1.z*xv.x; acc[6].y += e1.z*xv.y;
    acc[7].x += e1.w*xv.x; acc[7].y += e1.w*xv.y;
    acc[8].x += e2.x*xv.x; acc[8].y += e2.x*xv.y;
    acc[9].x += e2.y*xv.x; acc[9].y += e2.y*xv.y;
    acc[10].x += e2.z*xv.x; acc[10].y += e2.z*xv.y;
    acc[11].x += e2.w*xv.x; acc[11].y += e2.w*xv.y;
    acc[12].x += e3.x*xv.x; acc[12].y += e3.x*xv.y;
    acc[13].x += e3.y*xv.x; acc[13].y += e3.y*xv.y;
    acc[14].x += e3.z*xv.x; acc[14].y += e3.z*xv.y;
    acc[15].x += e3.w*xv.x; acc[15].y += e3.w*xv.y;
  }
  float2* Sp2 = (float2*)Spart;
  int ns2 = ns*2 + h;
  #pragma unroll
  for (int m = 0; m < MM; ++m)
    Sp2[(((size_t)ns2*BB + b)*MM + m)*256 + c2] = acc[m];
}

// ---------------------------------------------------------------------------
// S[row][c] = (sum_{ns2<32} Spart[ns2][row][c]) / (sum_{ns<16} dpart[ns][row]).
// grid 512, block 256 over 1024*128 float4.
__global__ void k_sreduce3(const float* __restrict__ Spart,
                           const float* __restrict__ dpart,
                           float* __restrict__ S) {
  int idx = blockIdx.x*256 + threadIdx.x;   // 0..131071
  int row = idx >> 7;                        // b*16+m
  const float4* Sp4 = (const float4*)Spart;
  float4 a = {0.f,0.f,0.f,0.f};
  #pragma unroll
  for (int ns2 = 0; ns2 < 32; ++ns2) {
    float4 v = Sp4[((size_t)ns2*NN + row)*128 + (idx & 127)];
    a.x += v.x; a.y += v.y; a.z += v.z; a.w += v.w;
  }
  float d = 0.f;
  #pragma unroll
  for (int ns = 0; ns < 16; ++ns) d += dpart[(size_t)ns*NN + row];
  float inv = 1.0f/d;
  float4 r = {a.x*inv, a.y*inv, a.z*inv, a.w*inv};
  ((float4*)S)[idx] = r;
}

// ---------------------------------------------------------------------------
// out[b,n,:] = sum_m PT[b,n,m]*G[b,m,:]. grid (32 nc, 64 b), block 256.
__global__ __launch_bounds__(256) void k_final5(const float* __restrict__ PT,
                                                const float* __restrict__ G,
                                                float* __restrict__ out) {
  __shared__ float ps[32*MM];    // 2 KB
  int nc = blockIdx.x, b = blockIdx.y, t = threadIdx.x;
  int col = t & 127, h = t >> 7;
  int n0 = nc*32;
  if (t < 128)
    ((float4*)ps)[t] = ((const float4*)(PT + ((size_t)b*NN + n0)*MM))[t];
  float4 g[MM];
  const float4* G4 = (const float4*)(G + (size_t)b*MM*CC);
  #pragma unroll
  for (int m = 0; m < MM; ++m) g[m] = G4[m*128 + col];
  __syncthreads();
  float4* out4 = (float4*)(out + ((size_t)b*NN + n0 + h*16)*CC);
  for (int i = 0; i < 16; ++i) {
    float4 o = {0.f,0.f,0.f,0.f};
    #pragma unroll
    for (int m = 0; m < MM; ++m) {
      float p = ps[(h*16 + i)*MM + m];
      o.x += p*g[m].x; o.y += p*g[m].y; o.z += p*g[m].z; o.w += p*g[m].w;
    }
    out4[(size_t)i*128 + col] = o;
  }
}

// ---------------------------------------------------------------------------
extern "C" void kernel_launch(void* const* d_in, const int* in_sizes, int n_in,
                              void* d_out, int out_size, void* d_ws, size_t ws_size,
                              hipStream_t stream) {
  (void)in_sizes; (void)n_in; (void)out_size; (void)ws_size;
  const float* x  = (const float*)d_in[0];
  const float* Wq = (const float*)d_in[1];
  const float* bq = (const float*)d_in[2];
  const float* Wk = (const float*)d_in[3];
  const float* bk = (const float*)d_in[4];
  const float* Wv = (const float*)d_in[5];
  const float* bv = (const float*)d_in[6];
  const float* Wo = (const float*)d_in[7];
  const float* bo = (const float*)d_in[8];
  float* out = (float*)d_out;

  float* ws  = (float*)d_ws;
  float* P     = ws;                      // 512K floats
  float* A     = P  + 1024*512;           // 512K  (A, AF, G contiguous: one memset)
  float* AF    = A  + 1024*512;           // 512K
  float* G     = AF + 1024*512;           // 512K
  float* Aq    = G  + 1024*512;           // 512K
  float* Ak    = Aq + 1024*512;           // 512K
  float* abq   = Ak + 1024*512;           // 1K
  float* abk   = abq + 1024;              // 1K
  float* PT    = abk + 1024;              // 1M  ([b][n][16])
  float* dpart = PT + 1024*1024;          // 16K ([ns][b][m])
  float* S     = dpart + 16*1024;         // 512K
  float* Spart = S + 1024*512;            // 16M ([ns2][b][m][512])

  hipMemsetAsync(A, 0, (size_t)3*1024*512*sizeof(float), stream);
  k_pool3<<<dim3(1024,2), 128, 0, stream>>>(x, P);
  k_gemm_nt4<<<dim3(8,16,4), 256, 0, stream>>>(P, Wq, bq, A);
  k_gemm_nn3<<<dim3(2,256), 256, 0, stream>>>(A, Wq, Wk, bq, bk, Aq, Ak, abq, abk);
  k_mega<<<dim3(16,64), 512, 0, stream>>>(x, Aq, Ak, abq, abk, PT, dpart, Spart);
  k_sreduce3<<<512, 256, 0, stream>>>(Spart, dpart, S);
  k_gemm_nt4<<<dim3(8,16,4), 256, 0, stream>>>(S, Wv, bv, AF);
  k_gemm_nt4<<<dim3(8,16,4), 256, 0, stream>>>(AF, Wo, bo, G);
  k_final5<<<dim3(32,64), 256, 0, stream>>>(PT, G, out);
}